// Round 2
// baseline (88.155 us; speedup 1.0000x reference)
//
#include <hip/hip_runtime.h>

#define D_MAX   50
#define T_DIM   51          // D_MAX + 1
#define B_DIM   16
#define P_DIM   2048
#define Q_DIM   2048
#define TPAD    64          // padded T: row (p) is 64*16 float2 = 8 KB
#define PT      16          // p-tile per transpose block
#define PCHUNK  16
#define NCHUNK  (P_DIM / PCHUNK)   // 128

// ws layout:
//   bufT2  : float2 [P][TPAD][B]   = 2048*64*16*8 = 16 MiB
//     bufT2[p][t][b] = (buf[b][t][p], buf[b][t+1][p]), zero-padded past T_DIM
//   partial: float  [NCHUNK][B][Q] = 128*16*2048*4 = 16 MiB

// Kernel 1: buf [B][T][P] -> bufT2 [P][TPAD][B] of (v[t], v[t+1]) float2 pairs.
// Block = (16 p's) x (8 b's): each block writes complete 64B lines
// (8 b * 8 B = 64 B per (p,t)).
__global__ __launch_bounds__(256) void dsl_transpose_kernel(
    const float* __restrict__ buf, float2* __restrict__ bufT2) {
    __shared__ float lds[8][T_DIM + 1][PT + 1];   // [b-local][t][p], pads break conflicts
    const int p0 = blockIdx.x * PT;
    const int b0 = blockIdx.y * 8;
    const int tid = threadIdx.x;

    // load: rows of 16 consecutive p (64B segments per 16 lanes)
    const int pp = tid & 15, r0 = tid >> 4;
    for (int bl = 0; bl < 8; ++bl)
        for (int t = r0; t < T_DIM; t += 16)
            lds[bl][t][pp] = buf[((size_t)((b0 + bl) * T_DIM + t)) * P_DIM + p0 + pp];
    __syncthreads();

    // store: per p, (t, b-local) pairs; 8 consecutive lanes write 64B contiguous
    const int bl = tid & 7, tb = tid >> 3;        // tb in 0..31
    for (int p = 0; p < PT; ++p) {
#pragma unroll
        for (int i = 0; i < 2; ++i) {
            const int t = tb + 32 * i;
            const float v0 = (t < T_DIM)     ? lds[bl][t][p]     : 0.f;
            const float v1 = (t + 1 < T_DIM) ? lds[bl][t + 1][p] : 0.f;
            bufT2[(((size_t)(p0 + p)) * TPAD + t) * B_DIM + b0 + bl] = make_float2(v0, v1);
        }
    }
}

// Kernel 2: thread = one q; 16 batch accumulators; inner loop = 8 float4 loads
// (the 16 (s_f,s_c) pairs for this (p, d_floor) are 128 contiguous bytes).
__global__ __launch_bounds__(256) void dsl_main_kernel(
    const float* __restrict__ W, const float* __restrict__ DR,
    const float2* __restrict__ bufT2, float* __restrict__ partial) {
    const int q  = blockIdx.x * 256 + threadIdx.x;
    const int p0 = blockIdx.y * PCHUNK;

    float acc[B_DIM];
#pragma unroll
    for (int b = 0; b < B_DIM; ++b) acc[b] = 0.f;

#pragma unroll 2
    for (int p = p0; p < p0 + PCHUNK; ++p) {
        const float w = W[(size_t)p * Q_DIM + q];
        const float x = DR[(size_t)p * Q_DIM + q];
        const float d = 50.f / (1.f + __expf(-x));   // D_MAX * sigmoid(x)
        const int df = min((int)d, D_MAX);
        const float a   = d - (float)df;
        const float wa  = w * a;                     // acc += (w-wa)*s_f + wa*s_c
        const float wna = w - wa;

        const float4* row = (const float4*)(bufT2 + ((size_t)p * TPAD + df) * B_DIM);
#pragma unroll
        for (int r = 0; r < 8; ++r) {
            const float4 v = row[r];                 // b=2r: (s_f,s_c), b=2r+1: (s_f,s_c)
            acc[2 * r]     = fmaf(wna, v.x, fmaf(wa, v.y, acc[2 * r]));
            acc[2 * r + 1] = fmaf(wna, v.z, fmaf(wa, v.w, acc[2 * r + 1]));
        }
    }

    float* dst = partial + (size_t)blockIdx.y * (B_DIM * Q_DIM) + q;
#pragma unroll
    for (int b = 0; b < B_DIM; ++b)
        dst[(size_t)b * Q_DIM] = acc[b];
}

// Kernel 3: sum NCHUNK partials; 4 waves split the chunk dim, LDS combine.
__global__ __launch_bounds__(256) void dsl_reduce_kernel(
    const float* __restrict__ partial, float* __restrict__ out) {
    __shared__ float lds[4][64];
    const int j = threadIdx.x & 63;
    const int w = threadIdx.x >> 6;
    const int idx = blockIdx.x * 64 + j;             // idx = b*Q + q
    float s = 0.f;
    for (int c = w; c < NCHUNK; c += 4)
        s += partial[(size_t)c * (B_DIM * Q_DIM) + idx];
    lds[w][j] = s;
    __syncthreads();
    if (w == 0)
        out[idx] = lds[0][j] + lds[1][j] + lds[2][j] + lds[3][j];
}

extern "C" void kernel_launch(void* const* d_in, const int* in_sizes, int n_in,
                              void* d_out, int out_size, void* d_ws, size_t ws_size,
                              hipStream_t stream) {
    const float* buf = (const float*)d_in[0];   // [B, T, P]
    const float* W   = (const float*)d_in[1];   // [P, Q]
    const float* DR  = (const float*)d_in[2];   // [P, Q]
    float* out = (float*)d_out;                 // [B, Q]

    char* ws = (char*)d_ws;
    float2* bufT2  = (float2*)ws;
    float* partial = (float*)(ws + (size_t)P_DIM * TPAD * B_DIM * sizeof(float2));

    hipLaunchKernelGGL(dsl_transpose_kernel, dim3(P_DIM / PT, 2), dim3(256), 0, stream,
                       buf, bufT2);
    hipLaunchKernelGGL(dsl_main_kernel, dim3(Q_DIM / 256, NCHUNK), dim3(256), 0, stream,
                       W, DR, bufT2, partial);
    hipLaunchKernelGGL(dsl_reduce_kernel, dim3((B_DIM * Q_DIM) / 64), dim3(256), 0, stream,
                       partial, out);
}

// Round 3
// 61.072 us; speedup vs baseline: 1.4434x; 1.4434x over previous
//
#include <hip/hip_runtime.h>

#define D_MAX   50
#define T_DIM   51          // D_MAX + 1
#define B_DIM   16
#define P_DIM   2048
#define Q_DIM   2048
#define TPAD    64          // padded T: one p-row = 64*16 float2 = 8 KB
#define PT      16          // p-tile per transpose block
#define PCHUNK  64
#define NCHUNK  (P_DIM / PCHUNK)   // 32
#define ROWB    (TPAD * B_DIM * 8) // 8192 bytes per p-row

// ws layout:
//   bufT2  : float2 [P][TPAD][B]   = 2048*64*16*8 = 16 MiB
//     bufT2[p][t][b] = (buf[b][t][p], buf[b][t+1][p]), zero-padded past T_DIM
//   partial: float  [NCHUNK][B][Q] = 32*16*2048*4 = 4 MiB

// Kernel 1: buf [B][T][P] -> bufT2 [P][TPAD][B] of (v[t], v[t+1]) float2 pairs.
__global__ __launch_bounds__(256) void dsl_transpose_kernel(
    const float* __restrict__ buf, float2* __restrict__ bufT2) {
    __shared__ float lds[8][T_DIM + 1][PT + 1];
    const int p0 = blockIdx.x * PT;
    const int b0 = blockIdx.y * 8;
    const int tid = threadIdx.x;

    const int pp = tid & 15, r0 = tid >> 4;
    for (int bl = 0; bl < 8; ++bl)
        for (int t = r0; t < T_DIM; t += 16)
            lds[bl][t][pp] = buf[((size_t)((b0 + bl) * T_DIM + t)) * P_DIM + p0 + pp];
    __syncthreads();

    const int bl = tid & 7, tb = tid >> 3;        // tb in 0..31
    for (int p = 0; p < PT; ++p) {
#pragma unroll
        for (int i = 0; i < 2; ++i) {
            const int t = tb + 32 * i;
            const float v0 = (t < T_DIM)     ? lds[bl][t][p]     : 0.f;
            const float v1 = (t + 1 < T_DIM) ? lds[bl][t + 1][p] : 0.f;
            bufT2[(((size_t)(p0 + p)) * TPAD + t) * B_DIM + b0 + bl] = make_float2(v0, v1);
        }
    }
}

// Kernel 2: block = 16 q x 16 b (b = fastest lane dim). Coef phase computes
// (wna, wa, df-byte-offset) per (p,q) once into LDS; main loop does one
// broadcast ds_read_b128 + one dense 128B-per-16-lane float2 gather + 2 FMA.
__global__ __launch_bounds__(256, 8) void dsl_main_kernel(
    const float* __restrict__ W, const float* __restrict__ DR,
    const float2* __restrict__ bufT2, float* __restrict__ partial) {
    __shared__ float4 coef[PCHUNK][16];     // (wna, wa, bitcast(df*128), 0)
    __shared__ float sAcc[B_DIM][17];
    const int tid = threadIdx.x;
    const int q0 = blockIdx.x * 16;
    const int p0 = blockIdx.y * PCHUNK;

    // ---- coef phase: thread (pl, qc), 16 consecutive qc lanes -> 64B loads
    {
        const int qc = tid & 15, pl0 = tid >> 4;
#pragma unroll
        for (int pl = pl0; pl < PCHUNK; pl += 16) {
            const size_t off = (size_t)(p0 + pl) * Q_DIM + q0 + qc;
            const float w = W[off];
            const float x = DR[off];
            const float d = 50.f / (1.f + __expf(-x));   // D_MAX * sigmoid(x)
            const int df = min((int)d, D_MAX);
            const float a  = d - (float)df;
            const float wa = w * a;
            coef[pl][qc] = make_float4(w - wa, wa,
                                       __int_as_float(df * (B_DIM * 8)), 0.f);
        }
    }
    __syncthreads();

    // ---- main loop: thread (qc, b); df uniform across the 16 b-lanes
    const int b = tid & 15, qc = tid >> 4;
    const char* prow = (const char*)bufT2 + (size_t)p0 * ROWB + b * 8;
    float acc = 0.f;
#pragma unroll 4
    for (int pl = 0; pl < PCHUNK; ++pl) {
        const float4 c = coef[pl][qc];
        const float2 s = *(const float2*)(prow + (size_t)pl * ROWB
                                          + __float_as_int(c.z));
        acc = fmaf(c.x, s.x, fmaf(c.y, s.y, acc));
    }

    // ---- coalesced partial write via LDS transpose
    sAcc[b][qc] = acc;
    __syncthreads();
    const int ob = tid >> 4, oq = tid & 15;
    partial[(size_t)blockIdx.y * (B_DIM * Q_DIM) + (size_t)ob * Q_DIM + q0 + oq]
        = sAcc[ob][oq];
}

// Kernel 3: sum NCHUNK partials; block = 64 outputs x 4 waves, LDS combine.
__global__ __launch_bounds__(256) void dsl_reduce_kernel(
    const float* __restrict__ partial, float* __restrict__ out) {
    __shared__ float lds[4][64];
    const int j = threadIdx.x & 63;
    const int w = threadIdx.x >> 6;
    const int idx = blockIdx.x * 64 + j;             // idx = b*Q + q
    float s = 0.f;
    for (int c = w; c < NCHUNK; c += 4)
        s += partial[(size_t)c * (B_DIM * Q_DIM) + idx];
    lds[w][j] = s;
    __syncthreads();
    if (w == 0)
        out[idx] = lds[0][j] + lds[1][j] + lds[2][j] + lds[3][j];
}

extern "C" void kernel_launch(void* const* d_in, const int* in_sizes, int n_in,
                              void* d_out, int out_size, void* d_ws, size_t ws_size,
                              hipStream_t stream) {
    const float* buf = (const float*)d_in[0];   // [B, T, P]
    const float* W   = (const float*)d_in[1];   // [P, Q]
    const float* DR  = (const float*)d_in[2];   // [P, Q]
    float* out = (float*)d_out;                 // [B, Q]

    char* ws = (char*)d_ws;
    float2* bufT2  = (float2*)ws;
    float* partial = (float*)(ws + (size_t)P_DIM * TPAD * B_DIM * sizeof(float2));

    hipLaunchKernelGGL(dsl_transpose_kernel, dim3(P_DIM / PT, 2), dim3(256), 0, stream,
                       buf, bufT2);
    hipLaunchKernelGGL(dsl_main_kernel, dim3(Q_DIM / 16, NCHUNK), dim3(256), 0, stream,
                       W, DR, bufT2, partial);
    hipLaunchKernelGGL(dsl_reduce_kernel, dim3((B_DIM * Q_DIM) / 64), dim3(256), 0, stream,
                       partial, out);
}

// Round 4
// 37.204 us; speedup vs baseline: 2.3695x; 1.6416x over previous
//
#include <hip/hip_runtime.h>

#define D_MAX   50
#define T_DIM   51
#define B_DIM   16
#define P_DIM   2048
#define Q_DIM   2048
#define TSTRIDE 80                      // bytes per t-row: 64 used + 16 bank-skew
#define PBYTES  4608                    // bytes per p-row: 52*80=4160 padded to 512-mult
#define PCHUNK  16                      // p's per LDS buffer
#define PSPAN   32                      // p's per block (2 chunks)
#define NPBLK   (P_DIM / PSPAN)         // 64
#define QB      512
#define CHUNK_BYTES (PCHUNK * PBYTES)   // 73728

// ws layout:
//   bufSw  : char [P][PBYTES]  = 9.4 MiB   pre-swizzled LDS image:
//            float at p*PBYTES + t*TSTRIDE + b*4  = buf[b][t][p]  (t=51 row = 0)
//   partial: float [NPBLK][B][Q] = 8 MiB

typedef const __attribute__((address_space(1))) void* gas_ptr;
typedef __attribute__((address_space(3))) void* las_ptr;
__device__ __forceinline__ void async_copy16(const char* g, char* l) {
    __builtin_amdgcn_global_load_lds((gas_ptr)g, (las_ptr)l, 16, 0, 0);
}

// Kernel 1: buf [B][T][P] -> bufSw swizzled image.
#define PT_TR 16
__global__ __launch_bounds__(256) void dsl_transpose_kernel(
    const float* __restrict__ buf, char* __restrict__ bufSw) {
    __shared__ float lds[B_DIM * T_DIM][PT_TR + 1];   // [816][17] = 55.5 KB
    const int p0 = blockIdx.x * PT_TR;
    const int tid = threadIdx.x;

    // load: rows r = b*51+t (matches buf's [B][T] flattening), 16 p lanes
    const int pp = tid & 15, j = tid >> 4;
    for (int r = j; r < B_DIM * T_DIM; r += 16)
        lds[r][pp] = buf[(size_t)r * P_DIM + p0 + pp];
    __syncthreads();

    // store: lane = b (16 fastest -> 64B segments), 16 p's per block
    const int bl = tid & 15, pl = tid >> 4;
    char* rowbase = bufSw + (size_t)(p0 + pl) * PBYTES + bl * 4;
    for (int t = 0; t < T_DIM + 1; ++t) {
        const float v = (t < T_DIM) ? lds[bl * T_DIM + t][pl] : 0.f;
        *(float*)(rowbase + t * TSTRIDE) = v;
    }
}

// Kernel 2: block = 512 q-lanes x 32 p (2 LDS chunks, double-buffered).
// Per thread: 1 q, 16 batch accumulators; per p: sigmoid once, 8 ds_read_b128
// (skewed rows -> spread banks), 32 FMA.
__global__ __launch_bounds__(512) void dsl_main_kernel(
    const float* __restrict__ W, const float* __restrict__ DR,
    const char* __restrict__ bufSw, float* __restrict__ partial) {
    __shared__ char lds[2 * CHUNK_BYTES];   // 144 KB
    const int tid = threadIdx.x;
    const int q   = blockIdx.x * QB + tid;
    const int p0  = blockIdx.y * PSPAN;
    const int wid = tid >> 6, lane = tid & 63;

    // fill chunk 0 (16 p-rows, 72 KB contiguous): 9 x (512 thr * 16B)
    {
        const char* src = bufSw + (size_t)p0 * PBYTES;
#pragma unroll
        for (int i = 0; i < 9; ++i) {
            const int off = i * 8192 + wid * 1024;          // wave-uniform LDS dest
            async_copy16(src + off + lane * 16, lds + off);
        }
    }
    __syncthreads();

    float acc[B_DIM];
#pragma unroll
    for (int b = 0; b < B_DIM; ++b) acc[b] = 0.f;

#pragma unroll 1
    for (int c = 0; c < 2; ++c) {
        if (c == 0) {   // issue chunk-1 fill; latency hides under chunk-0 compute
            const char* src = bufSw + (size_t)(p0 + PCHUNK) * PBYTES;
#pragma unroll
            for (int i = 0; i < 9; ++i) {
                const int off = i * 8192 + wid * 1024;
                async_copy16(src + off + lane * 16, lds + CHUNK_BYTES + off);
            }
        }
        const char* cbase = lds + c * CHUNK_BYTES;
        const float* Wp  = W  + (size_t)(p0 + c * PCHUNK) * Q_DIM + q;
        const float* DRp = DR + (size_t)(p0 + c * PCHUNK) * Q_DIM + q;

#pragma unroll 4
        for (int pl = 0; pl < PCHUNK; ++pl) {
            const float w = Wp[pl * Q_DIM];
            const float x = DRp[pl * Q_DIM];
            const float d = 50.f / (1.f + __expf(-x));      // D_MAX * sigmoid
            const int df = min((int)d, D_MAX);
            const float a   = d - (float)df;
            const float wa  = w * a;
            const float wna = w - wa;

            const char* rb = cbase + pl * PBYTES + df * TSTRIDE;
            const float4 f0 = *(const float4*)(rb);
            const float4 f1 = *(const float4*)(rb + 16);
            const float4 f2 = *(const float4*)(rb + 32);
            const float4 f3 = *(const float4*)(rb + 48);
            const float4 c0 = *(const float4*)(rb + TSTRIDE);
            const float4 c1 = *(const float4*)(rb + TSTRIDE + 16);
            const float4 c2 = *(const float4*)(rb + TSTRIDE + 32);
            const float4 c3 = *(const float4*)(rb + TSTRIDE + 48);

            acc[0]  = fmaf(wna, f0.x, fmaf(wa, c0.x, acc[0]));
            acc[1]  = fmaf(wna, f0.y, fmaf(wa, c0.y, acc[1]));
            acc[2]  = fmaf(wna, f0.z, fmaf(wa, c0.z, acc[2]));
            acc[3]  = fmaf(wna, f0.w, fmaf(wa, c0.w, acc[3]));
            acc[4]  = fmaf(wna, f1.x, fmaf(wa, c1.x, acc[4]));
            acc[5]  = fmaf(wna, f1.y, fmaf(wa, c1.y, acc[5]));
            acc[6]  = fmaf(wna, f1.z, fmaf(wa, c1.z, acc[6]));
            acc[7]  = fmaf(wna, f1.w, fmaf(wa, c1.w, acc[7]));
            acc[8]  = fmaf(wna, f2.x, fmaf(wa, c2.x, acc[8]));
            acc[9]  = fmaf(wna, f2.y, fmaf(wa, c2.y, acc[9]));
            acc[10] = fmaf(wna, f2.z, fmaf(wa, c2.z, acc[10]));
            acc[11] = fmaf(wna, f2.w, fmaf(wa, c2.w, acc[11]));
            acc[12] = fmaf(wna, f3.x, fmaf(wa, c3.x, acc[12]));
            acc[13] = fmaf(wna, f3.y, fmaf(wa, c3.y, acc[13]));
            acc[14] = fmaf(wna, f3.z, fmaf(wa, c3.z, acc[14]));
            acc[15] = fmaf(wna, f3.w, fmaf(wa, c3.w, acc[15]));
        }
        __syncthreads();   // drains chunk-1 fill (vmcnt) before c=1 compute
    }

    float* dst = partial + (size_t)blockIdx.y * (B_DIM * Q_DIM) + q;
#pragma unroll
    for (int b = 0; b < B_DIM; ++b)
        dst[(size_t)b * Q_DIM] = acc[b];    // coalesced along q
}

// Kernel 3: sum NPBLK partials; 64 outputs x 4 c-waves, LDS combine.
__global__ __launch_bounds__(256) void dsl_reduce_kernel(
    const float* __restrict__ partial, float* __restrict__ out) {
    __shared__ float lds[4][64];
    const int j = threadIdx.x & 63, w = threadIdx.x >> 6;
    const int idx = blockIdx.x * 64 + j;            // idx = b*Q + q
    float s = 0.f;
    for (int c = w; c < NPBLK; c += 4)
        s += partial[(size_t)c * (B_DIM * Q_DIM) + idx];
    lds[w][j] = s;
    __syncthreads();
    if (w == 0)
        out[idx] = lds[0][j] + lds[1][j] + lds[2][j] + lds[3][j];
}

extern "C" void kernel_launch(void* const* d_in, const int* in_sizes, int n_in,
                              void* d_out, int out_size, void* d_ws, size_t ws_size,
                              hipStream_t stream) {
    const float* buf = (const float*)d_in[0];   // [B, T, P]
    const float* W   = (const float*)d_in[1];   // [P, Q]
    const float* DR  = (const float*)d_in[2];   // [P, Q]
    float* out = (float*)d_out;                 // [B, Q]

    char* ws = (char*)d_ws;
    char*  bufSw   = ws;
    float* partial = (float*)(ws + (size_t)P_DIM * PBYTES);

    hipLaunchKernelGGL(dsl_transpose_kernel, dim3(P_DIM / PT_TR), dim3(256), 0, stream,
                       buf, bufSw);
    hipLaunchKernelGGL(dsl_main_kernel, dim3(Q_DIM / QB, NPBLK), dim3(512), 0, stream,
                       W, DR, bufSw, partial);
    hipLaunchKernelGGL(dsl_reduce_kernel, dim3((B_DIM * Q_DIM) / 64), dim3(256), 0, stream,
                       partial, out);
}